// Round 5
// baseline (222.520 us; speedup 1.0000x reference)
//
#include <hip/hip_runtime.h>
#include <math.h>

#define NPTS 500000
#define TSIZE 524288u
#define TMASK (TSIZE - 1u)
#define CHUNKS 1954        // ceil(NPTS/256)
#define SLICE 245          // ceil(CHUNKS/8): pool-level chunks per XCD
#define POOL_LVLS 6        // pooled levels 2..7 (0,1 go to LDS-staged kernels)

struct ResArgs { float r[16]; };

// Per-(point,level): 8 corner gathers with float4 x-pairing + trilinear blend.
__device__ __forceinline__ float2 mhe_point_level(
    const float* __restrict__ x, const float* __restrict__ tbl,
    int p, int l, float res)
{
    float x0 = x[p * 3 + 0];
    float x1 = x[p * 3 + 1];
    float x2 = x[p * 3 + 2];

    float s0 = x0 * res, s1 = x1 * res, s2 = x2 * res;
    float f0 = floorf(s0), f1 = floorf(s1), f2 = floorf(s2);
    float w0 = s0 - f0, w1 = s1 - f1, w2 = s2 - f2;
    unsigned u0 = (unsigned)f0, u1 = (unsigned)f1, u2 = (unsigned)f2;

    unsigned b0 = u1 * 2654435761u, b1 = (u1 + 1u) * 2654435761u;
    unsigned c0 = u2 * 805459861u,  c1 = (u2 + 1u) * 805459861u;

    const float2* t  = (const float2*)tbl + (size_t)l * TSIZE;
    const float4* t4 = (const float4*)t;

    float v0a = 1.f - w0, v0b = w0;
    float v1a = 1.f - w1, v1b = w1;
    float v2a = 1.f - w2, v2b = w2;

    bool odd = (u0 & 1u) != 0u;
    unsigned u0p1 = u0 + 1u;

    float o0 = 0.f, o1 = 0.f;
#pragma unroll
    for (int j = 0; j < 4; ++j) {               // j bits: (j&1)=dy, (j&2)=dz
        unsigned bc = ((j & 1) ? b1 : b0) ^ ((j & 2) ? c1 : c0);
        unsigned e0 = (u0 ^ bc) & TMASK;
        float4 q = t4[e0 >> 1];                 // entries {e0&~1, e0|1}
        float2 lo = make_float2(q.x, q.y);
        float2 hi = make_float2(q.z, q.w);
        float2 fc0 = (e0 & 1u) ? hi : lo;
        float2 fc1 = (e0 & 1u) ? lo : hi;       // valid iff u0 even
        if (odd) {                              // predicated odd-lane fixup
            unsigned e1 = (u0p1 ^ bc) & TMASK;
            fc1 = t[e1];
        }
        float wyz = ((j & 1) ? v1b : v1a) * ((j & 2) ? v2b : v2a);
        o0 = fmaf(v0a * wyz, fc0.x, o0);
        o1 = fmaf(v0a * wyz, fc0.y, o1);
        o0 = fmaf(v0b * wyz, fc1.x, o0);
        o1 = fmaf(v0b * wyz, fc1.y, o1);
    }
    return make_float2(o0, o1);
}

// ---- Main gather: fine anchors + pooled mid levels -----------------------
// blockIdx%8 -> XCD. Phase A: XCD x owns fine level 8+x (4MB = its L2).
// Phase B: levels 2..7 pooled level-major, 1/8 of chunks per XCD.
__global__ __launch_bounds__(256) void mhe_gather(
    const float* __restrict__ x,
    const float* __restrict__ tbl,
    float2* __restrict__ ws,
    ResArgs ra)
{
    int b = blockIdx.x;
    int xcd = b & 7;
    int t = b >> 3;
    int l, chunk;
    if (t < CHUNKS) {               // Phase A: anchored fine level
        l = 8 + xcd;
        chunk = t;
    } else {                        // Phase B: pooled levels 2..7
        int u = t - CHUNKS;
        int pl = u / SLICE;
        int sc = u - pl * SLICE;
        l = 2 + pl;
        chunk = xcd * SLICE + sc;
        if (chunk >= CHUNKS) return;
    }
    int p = chunk * 256 + threadIdx.x;
    if (p >= NPTS) return;

    float2 o = mhe_point_level(x, tbl, p, l, ra.r[l]);
    ws[(size_t)l * NPTS + p] = o;
}

// ---- LDS-staged levels 0,1 -----------------------------------------------
// Hash structure: e = u0 ^ (u1*P1 ^ u2*P2) with u0 < 32 stays inside the
// 32-entry aligned block of bc = u1*P1^u2*P2. So level l's WHOLE table is
// RESI^2 blocks of 32 entries: l0 (RESI=17) 74KB, l1 (RESI=21) 110KB -> LDS.
// Stage coalesced once per 1024-point workgroup, gather from LDS (free pipe),
// removing ~6M L2 line-requests from the request-rate-bound main kernel.
template <int LVL, int RESI>
__global__ __launch_bounds__(1024) void mhe_staged(
    const float* __restrict__ x,
    const float* __restrict__ tbl,
    float2* __restrict__ ws,
    float res)
{
    extern __shared__ float2 st[];   // RESI*RESI*32 entries
    const float2* t = (const float2*)tbl + (size_t)LVL * TSIZE;
    int tid = threadIdx.x;

    // stage: group g (32 threads) copies block b: st[b*32+i] = t[base+i]
    for (int b = tid >> 5; b < RESI * RESI; b += 32) {
        unsigned u1 = (unsigned)(b / RESI), u2 = (unsigned)(b % RESI);
        unsigned base = ((u1 * 2654435761u) ^ (u2 * 805459861u)) & TMASK & ~31u;
        st[b * 32 + (tid & 31)] = t[base + (tid & 31)];
    }
    __syncthreads();

    int p = blockIdx.x * 1024 + tid;
    if (p >= NPTS) return;

    float x0 = x[p * 3 + 0];
    float x1 = x[p * 3 + 1];
    float x2 = x[p * 3 + 2];
    float s0 = x0 * res, s1 = x1 * res, s2 = x2 * res;
    float f0 = floorf(s0), f1 = floorf(s1), f2 = floorf(s2);
    float w0 = s0 - f0, w1 = s1 - f1, w2 = s2 - f2;
    unsigned u0 = (unsigned)f0, u1 = (unsigned)f1, u2 = (unsigned)f2;

    unsigned b0 = u1 * 2654435761u, b1 = (u1 + 1u) * 2654435761u;
    unsigned c0 = u2 * 805459861u,  c1 = (u2 + 1u) * 805459861u;

    float v0a = 1.f - w0, v0b = w0;
    float v1a = 1.f - w1, v1b = w1;
    float v2a = 1.f - w2, v2b = w2;

    float o0 = 0.f, o1 = 0.f;
#pragma unroll
    for (int j = 0; j < 4; ++j) {               // (j&1)=dy, (j&2)=dz
        unsigned u1c = u1 + ((j & 1) ? 1u : 0u);
        unsigned u2c = u2 + ((j & 2) ? 1u : 0u);
        unsigned bc = ((j & 1) ? b1 : b0) ^ ((j & 2) ? c1 : c0);
        int blk = (int)(u1c * RESI + u2c) * 32;
        unsigned bc5 = bc & 31u;
        float2 fc0 = st[blk + (int)(u0 ^ bc5)];
        float2 fc1 = st[blk + (int)((u0 + 1u) ^ bc5)];
        float wyz = ((j & 1) ? v1b : v1a) * ((j & 2) ? v2b : v2a);
        o0 = fmaf(v0a * wyz, fc0.x, o0);
        o1 = fmaf(v0a * wyz, fc0.y, o1);
        o0 = fmaf(v0b * wyz, fc1.x, o0);
        o1 = fmaf(v0b * wyz, fc1.y, o1);
    }
    ws[(size_t)LVL * NPTS + p] = make_float2(o0, o1);
}

// ---- ws[level][point] -> out[point][level] LDS-tile transpose ------------
__global__ __launch_bounds__(256) void mhe_transpose(
    const float2* __restrict__ ws, float2* __restrict__ out)
{
    __shared__ float2 tile[16][65];
    int p0 = blockIdx.x * 64;
    int t = threadIdx.x;

    int pc = t & 63;
#pragma unroll
    for (int i = 0; i < 4; ++i) {
        int l = (t >> 6) + i * 4;
        int p = p0 + pc;
        if (p < NPTS) tile[l][pc] = ws[(size_t)l * NPTS + p];
    }
    __syncthreads();

#pragma unroll
    for (int i = 0; i < 4; ++i) {
        int pp = (t >> 4) + i * 16;
        int l = t & 15;
        int p = p0 + pp;
        if (p < NPTS) out[(size_t)p * 16 + l] = tile[l][pp];
    }
}

// ---- Fallback: direct-out single kernel (if ws too small) ----------------
__global__ __launch_bounds__(256) void mhe_kernel(
    const float* __restrict__ x,
    const float* __restrict__ tbl,
    float* __restrict__ out,
    ResArgs ra)
{
    int gid = blockIdx.x * 256 + threadIdx.x;
    int p = gid >> 4;
    int l = gid & 15;
    if (p >= NPTS) return;
    float2 o = mhe_point_level(x, tbl, p, l, ra.r[l]);
    ((float2*)out)[(size_t)p * 16 + l] = o;
}

extern "C" void kernel_launch(void* const* d_in, const int* in_sizes, int n_in,
                              void* d_out, int out_size, void* d_ws, size_t ws_size,
                              hipStream_t stream) {
    const float* x   = (const float*)d_in[0];
    const float* tbl = (const float*)d_in[1];
    float* out = (float*)d_out;

    // RES computed on HOST with libm doubles (bit-exact vs numpy): levels
    // 3,6,9,12,15 land exactly on 32/64/128/256/512; device ulp flips floor().
    ResArgs ra;
    double bb = exp((log(512.0) - log(16.0)) / 15.0);
    for (int l = 0; l < 16; ++l)
        ra.r[l] = (float)floor(16.0 * pow(bb, (double)l));

    size_t ws_needed = (size_t)NPTS * 16 * sizeof(float2);  // 64 MB
    if (ws_size >= ws_needed) {
        // raise dynamic-LDS cap for the staged kernels (idempotent, non-stream)
        (void)hipFuncSetAttribute((const void*)mhe_staged<0, 17>,
                                  hipFuncAttributeMaxDynamicSharedMemorySize,
                                  17 * 17 * 32 * (int)sizeof(float2));
        (void)hipFuncSetAttribute((const void*)mhe_staged<1, 21>,
                                  hipFuncAttributeMaxDynamicSharedMemorySize,
                                  21 * 21 * 32 * (int)sizeof(float2));

        int tasks_per_xcd = CHUNKS + POOL_LVLS * SLICE;   // 1954 + 1470
        mhe_gather<<<8 * tasks_per_xcd, 256, 0, stream>>>(x, tbl, (float2*)d_ws, ra);

        int sb = (NPTS + 1023) / 1024;   // 489
        mhe_staged<0, 17><<<sb, 1024, 17 * 17 * 32 * sizeof(float2), stream>>>(
            x, tbl, (float2*)d_ws, ra.r[0]);
        mhe_staged<1, 21><<<sb, 1024, 21 * 21 * 32 * sizeof(float2), stream>>>(
            x, tbl, (float2*)d_ws, ra.r[1]);

        mhe_transpose<<<(NPTS + 63) / 64, 256, 0, stream>>>((const float2*)d_ws,
                                                            (float2*)out);
    } else {
        mhe_kernel<<<(NPTS * 16 + 255) / 256, 256, 0, stream>>>(x, tbl, out, ra);
    }
}